// Round 4
// baseline (292.221 us; speedup 1.0000x reference)
//
#include <hip/hip_runtime.h>
#include <math.h>

#define B_ 32
#define N_ 64
#define K_ 128
#define NPAIR (B_*N_*N_)

typedef __attribute__((ext_vector_type(8))) short short8;
typedef __attribute__((ext_vector_type(8))) __bf16 bf16x8;
typedef __attribute__((ext_vector_type(4))) float floatx4;

__device__ __forceinline__ float silu_f(float x) {
    return x / (1.0f + expf(-x));
}
__device__ __forceinline__ float4 ld4(const float* p) { return *(const float4*)p; }

__device__ __forceinline__ short f2bf(float x) {
    union { float f; unsigned u; } v; v.f = x;
    unsigned r = (v.u + 0x7FFFu + ((v.u >> 16) & 1u)) >> 16;
    return (short)r;
}
__device__ __forceinline__ float bf2f(short s) {
    union { unsigned u; float f; } v;
    v.u = ((unsigned)(unsigned short)s) << 16;
    return v.f;
}
__device__ __forceinline__ bf16x8 ld_frag(const short* p) {
    short8 r = *(const short8*)p;
    return __builtin_bit_cast(bf16x8, r);
}

// ---------------------------------------------------------------------------
// Kernel 0: weight prep -> bf16 layouts. Section map (short offsets):
//   0       r1w1T [64n][64k]
//   4096    r1w2T [64n][64k]
//   8192    r2w1T [64n][64k]
//   12288   r2w2T [64n][64k]
//   16384   r2w3T [256n][64k]
//   32768   wT0   [512n][704k] (zero pad k>=641)
//   393216  wT1   [512n][512k]
//   655360  w0T1  [64n][32k]  (zero pad k>=8)
//   657408  w0T2  [64n][32k]
//   659456  w3T1  [384col][64h]  = r1w3[h][col]*wemb[col&127]/16
//   684032  lT    [128n][384k]  = stacked [l0; l2; l1]
//   733184  end
// ---------------------------------------------------------------------------
__global__ __launch_bounds__(256) void prep_kernel(
    const float* __restrict__ r1w0, const float* __restrict__ r1w1,
    const float* __restrict__ r1w2, const float* __restrict__ r1w3,
    const float* __restrict__ r2w0, const float* __restrict__ r2w1,
    const float* __restrict__ r2w2, const float* __restrict__ r2w3,
    const float* __restrict__ mw0, const float* __restrict__ mw1,
    const float* __restrict__ wemb,
    const float* __restrict__ l0, const float* __restrict__ l1,
    const float* __restrict__ l2, short* __restrict__ dst)
{
    int idx = blockIdx.x * 256 + threadIdx.x;
    if (idx >= 733184) return;
    short v;
    if (idx < 4096) {
        int n = idx >> 6, k = idx & 63; v = f2bf(r1w1[k*64 + n]);
    } else if (idx < 8192) {
        int i = idx - 4096; int n = i >> 6, k = i & 63; v = f2bf(r1w2[k*64 + n]);
    } else if (idx < 12288) {
        int i = idx - 8192; int n = i >> 6, k = i & 63; v = f2bf(r2w1[k*64 + n]);
    } else if (idx < 16384) {
        int i = idx - 12288; int n = i >> 6, k = i & 63; v = f2bf(r2w2[k*64 + n]);
    } else if (idx < 32768) {
        int i = idx - 16384; int col = i >> 6, h = i & 63; v = f2bf(r2w3[h*256 + col]);
    } else if (idx < 393216) {
        int i = idx - 32768; int n = i / 704, k = i - n*704;
        v = (k < 641) ? f2bf(mw0[(size_t)k*512 + n]) : (short)0;
    } else if (idx < 655360) {
        int i = idx - 393216; int n = i >> 9, k = i & 511;
        v = f2bf(mw1[(size_t)k*512 + n]);
    } else if (idx < 657408) {
        int i = idx - 655360; int n = i >> 5, k = i & 31;
        v = (k < 8) ? f2bf(r1w0[k*64 + n]) : (short)0;
    } else if (idx < 659456) {
        int i = idx - 657408; int n = i >> 5, k = i & 31;
        v = (k < 8) ? f2bf(r2w0[k*64 + n]) : (short)0;
    } else if (idx < 684032) {
        int i = idx - 659456; int col = i >> 6, h = i & 63;
        v = f2bf(r1w3[h*384 + col] * wemb[col & 127] * 0.0625f);
    } else {
        int i = idx - 684032; int n = i / 384, k = i - n*384;
        float f;
        if (k < 128)       f = l0[k*128 + n];
        else if (k < 256)  f = l2[(k-128)*128 + n];
        else               f = l1[(k-256)*128 + n];
        v = f2bf(f);
    }
    dst[idx] = v;
}

// ---------------------------------------------------------------------------
// Kernel 1: per-pair geometry -> rad[8], Y1[3], Y2[5], maskf  (fp32)
// sin(n*w) via recurrence: 1 sinf + 1 cosf + FMAs.
// ---------------------------------------------------------------------------
__global__ __launch_bounds__(256) void geom_kernel(
    const float* __restrict__ pos, const float* __restrict__ cell,
    float* __restrict__ rad, float* __restrict__ Y1, float* __restrict__ Y2,
    float* __restrict__ maskf)
{
    int p = blockIdx.x * 256 + threadIdx.x;
    if (p >= NPAIR) return;
    int b = p >> 12;
    int ij = p & 4095;
    int i = ij >> 6, j = ij & 63;
    const float* pi = pos + (size_t)(b*N_ + i)*3;
    const float* pj = pos + (size_t)(b*N_ + j)*3;
    float d0 = pi[0]-pj[0], d1 = pi[1]-pj[1], d2 = pi[2]-pj[2];
    d0 -= rintf(d0); d1 -= rintf(d1); d2 -= rintf(d2);
    const float* C = cell + b*9;
    float dc0 = d0*C[0] + d1*C[3] + d2*C[6];
    float dc1 = d0*C[1] + d1*C[4] + d2*C[7];
    float dc2 = d0*C[2] + d1*C[5] + d2*C[8];
    float r2 = fmaxf(dc0*dc0 + dc1*dc1 + dc2*dc2, 1e-12f);
    float r = sqrtf(r2);
    bool m = (r < 5.0f) && (i != j);
    float mf = m ? 1.0f : 0.0f;
    float rs = m ? r : 1.0f;
    float inv_rs = 1.0f / rs;
    float x = dc0*inv_rs*mf, y = dc1*inv_rs*mf, z = dc2*inv_rs*mf;
    float u = r * 0.2f;
    float u2 = u*u, u4 = u2*u2, u5 = u4*u;
    float fc = 1.0f - 21.0f*u5 + 35.0f*u5*u - 15.0f*u5*u2;
    fc = (u < 1.0f) ? fc : 0.0f;
    float pref = 0.6324555320336759f * inv_rs * (fc * mf);
    float w = 0.6283185307179586f * rs;
    float sw = sinf(w), cw = cosf(w);
    float c2 = 2.0f * cw;
    float rr[8];
    float sp = 0.f, s = sw;
    #pragma unroll
    for (int n = 0; n < 8; n++) {
        rr[n] = pref * s;
        float ns = c2*s - sp;
        sp = s; s = ns;
    }
    float4 v0 = {rr[0], rr[1], rr[2], rr[3]};
    float4 v1 = {rr[4], rr[5], rr[6], rr[7]};
    *(float4*)&rad[(size_t)p*8]     = v0;
    *(float4*)&rad[(size_t)p*8 + 4] = v1;
    const float s3  = 1.7320508075688772f;
    const float s5  = 2.23606797749979f;
    const float s15 = 3.872983346207417f;
    float* y1 = Y1 + (size_t)p*3;
    y1[0] = s3*x; y1[1] = s3*y; y1[2] = s3*z;
    float* y2 = Y2 + (size_t)p*5;
    y2[0] = s15*x*y;
    y2[1] = s15*y*z;
    y2[2] = 0.5f*s5*(3.0f*z*z - 1.0f);
    y2[3] = s15*x*z;
    y2[4] = 0.5f*s15*(x*x - y*y);
    maskf[p] = mf;
}

// ---------------------------------------------------------------------------
// MFMA MLP layer: src[64][72]bf16 @ WT[64n][64k]bf16(global) + bias -> silu
// -> dst[64][72]bf16.  transposeOut: dst[col][row] instead.
// ---------------------------------------------------------------------------
template<bool TRANSPOSE_OUT>
__device__ __forceinline__ void mfma_layer_t(
    const short* __restrict__ src, const short* __restrict__ WT,
    const float* __restrict__ bias, short* __restrict__ dst,
    int wv, int qd, int nn)
{
    floatx4 acc[4];
    #pragma unroll
    for (int tt = 0; tt < 4; tt++) acc[tt] = (floatx4){0.f, 0.f, 0.f, 0.f};
    #pragma unroll
    for (int ks = 0; ks < 64; ks += 32) {
        bf16x8 a = ld_frag(&src[(wv*16 + nn)*72 + ks + qd*8]);
        #pragma unroll
        for (int tt = 0; tt < 4; tt++) {
            bf16x8 b = ld_frag(&WT[(tt*16 + nn)*64 + ks + qd*8]);
            acc[tt] = __builtin_amdgcn_mfma_f32_16x16x32_bf16(a, b, acc[tt], 0, 0, 0);
        }
    }
    #pragma unroll
    for (int tt = 0; tt < 4; tt++) {
        int col = tt*16 + nn;
        float bv = bias[col];
        #pragma unroll
        for (int i = 0; i < 4; i++) {
            int row = wv*16 + qd*4 + i;
            short val = f2bf(silu_f(acc[tt][i] + bv));
            if (TRANSPOSE_OUT) dst[col*72 + row] = val;
            else               dst[row*72 + col] = val;
        }
    }
}

// L0: radB[64][40]bf16 (K=32 padded from 8) @ w0T[64n][32k] -> silu -> dst[64][72]
__device__ __forceinline__ void mfma_layer0(
    const short* __restrict__ radB, const short* __restrict__ w0T,
    const float* __restrict__ bias, short* __restrict__ dst,
    int wv, int qd, int nn)
{
    bf16x8 a = ld_frag(&radB[(wv*16 + nn)*40 + qd*8]);
    #pragma unroll
    for (int tt = 0; tt < 4; tt++) {
        floatx4 acc = (floatx4){0.f, 0.f, 0.f, 0.f};
        bf16x8 b = ld_frag(&w0T[(tt*16 + nn)*32 + qd*8]);
        acc = __builtin_amdgcn_mfma_f32_16x16x32_bf16(a, b, acc, 0, 0, 0);
        int col = tt*16 + nn;
        float bv = bias[col];
        #pragma unroll
        for (int i = 0; i < 4; i++) {
            int row = wv*16 + qd*4 + i;
            dst[row*72 + col] = f2bf(silu_f(acc[i] + bv));
        }
    }
}

// ---------------------------------------------------------------------------
// Kernel 2 (pass 1): one block per node. Everything GEMM-shaped on MFMA.
// ---------------------------------------------------------------------------
__global__ __launch_bounds__(256) void pass1_kernel(
    const float* __restrict__ rad, const float* __restrict__ Y1g,
    const float* __restrict__ Y2g, const float* __restrict__ maskg,
    const float* __restrict__ wemb,
    const short* __restrict__ w0T, const float* __restrict__ b0,
    const short* __restrict__ w1T, const float* __restrict__ b1,
    const short* __restrict__ w2T, const float* __restrict__ b2,
    const short* __restrict__ w3T, const float* __restrict__ b3,
    const short* __restrict__ lT, const float* __restrict__ timeg,
    float* __restrict__ h1g, float* __restrict__ v1g, short* __restrict__ featsb)
{
    // LDS pool with lifetime-based aliasing (offsets in bytes):
    //  radB [0,5120)       P0 -> L0
    //  hcT  [0,9216)       L2 -> G          (radB dead)
    //  actA [9216,18432)   L0 -> L1
    //  actB [18432,27648)  L1 -> L2
    //  A2   [9216,21760)   built late       (actA/actB dead)
    //  msgF [21760,26368)  fp32 [9*128]     (actB dead)
    //  YmB  [27648,29952)  [16*72]
    //  GB   [29952,32256)  [16*72]
    //  qF   [32256,32768)  fp32 [128]
    //  SY   [32768,32832)  fp32 [16]
    __shared__ __align__(16) char pool[32832];
    short* radB = (short*)pool;
    short* hcT  = (short*)pool;
    short* actA = (short*)(pool + 9216);
    short* actB = (short*)(pool + 18432);
    short* A2   = (short*)(pool + 9216);
    float* msgF = (float*)(pool + 21760);
    short* YmB  = (short*)(pool + 27648);
    short* GB   = (short*)(pool + 29952);
    float* qF   = (float*)(pool + 32256);
    float* SY   = (float*)(pool + 32768);

    int t = threadIdx.x;
    int wv = t >> 6, lane = t & 63, qd = lane >> 4, nn = lane & 15;
    int node = blockIdx.x;
    int b = node >> 6;
    size_t pbase = (size_t)node * 64;

    // P0: stage radB (zero-padded) and zero YmB
    for (int idx = t; idx < 2560; idx += 256) {
        int j = idx / 40, c = idx - j*40;
        radB[idx] = (c < 8) ? f2bf(rad[pbase*8 + j*8 + c]) : (short)0;
    }
    for (int idx = t; idx < 1152; idx += 256) YmB[idx] = 0;
    __syncthreads();

    // Ym fill (bf16) + L0 MFMA in the same phase (independent regions)
    if (t < 64) {
        int j = t;
        float mf = maskg[pbase + j];
        YmB[j] = f2bf(mf);
        #pragma unroll
        for (int m = 0; m < 3; m++) YmB[(1+m)*72 + j] = f2bf(Y1g[(pbase+j)*3 + m] * mf);
        #pragma unroll
        for (int m = 0; m < 5; m++) YmB[(4+m)*72 + j] = f2bf(Y2g[(pbase+j)*5 + m] * mf);
    }
    mfma_layer0(radB, w0T, b0, actA, wv, qd, nn);
    __syncthreads();

    mfma_layer_t<false>(actA, w1T, b1, actB, wv, qd, nn);
    __syncthreads();
    mfma_layer_t<true >(actB, w2T, b2, hcT,  wv, qd, nn);   // hcT[h][j]
    __syncthreads();

    // SY + G GEMM: G[16m][64h] = Ym[16m][64j] @ hcT(B: n=h, k=j)
    if (t < 16) {
        float acc = 0.f;
        if (t < 9) for (int j = 0; j < 64; j++) acc += bf2f(YmB[t*72 + j]);
        SY[t] = acc;
    }
    {
        floatx4 accG = (floatx4){0.f, 0.f, 0.f, 0.f};
        #pragma unroll
        for (int ks = 0; ks < 64; ks += 32) {
            bf16x8 a = ld_frag(&YmB[nn*72 + ks + qd*8]);
            bf16x8 bfr = ld_frag(&hcT[(wv*16 + nn)*72 + ks + qd*8]);
            accG = __builtin_amdgcn_mfma_f32_16x16x32_bf16(a, bfr, accG, 0, 0, 0);
        }
        #pragma unroll
        for (int i = 0; i < 4; i++)
            GB[(qd*4 + i)*72 + wv*16 + nn] = f2bf(accG[i]);
    }
    __syncthreads();

    // msgD GEMM: D[16m][384col] = GB @ w3T (wemb/16 folded); extract diagonal
    // blocks: msg[m][k] = D[m][c(m)*128+k] + SY[m]*b3[col]*wemb[k]/16
    {
        bf16x8 a0f = ld_frag(&GB[nn*72 + 0  + qd*8]);
        bf16x8 a1f = ld_frag(&GB[nn*72 + 32 + qd*8]);
        #pragma unroll
        for (int tl = 0; tl < 6; tl++) {
            int col0 = (wv*6 + tl)*16;
            floatx4 acc = (floatx4){0.f, 0.f, 0.f, 0.f};
            bf16x8 b0f = ld_frag(&w3T[(col0 + nn)*64 + 0  + qd*8]);
            bf16x8 b1f = ld_frag(&w3T[(col0 + nn)*64 + 32 + qd*8]);
            acc = __builtin_amdgcn_mfma_f32_16x16x32_bf16(a0f, b0f, acc, 0, 0, 0);
            acc = __builtin_amdgcn_mfma_f32_16x16x32_bf16(a1f, b1f, acc, 0, 0, 0);
            int col = col0 + nn;
            int csec = col >> 7, k = col & 127;
            #pragma unroll
            for (int i = 0; i < 4; i++) {
                int m = qd*4 + i;
                bool valid = (csec == 0) ? (m == 0)
                           : (csec == 1) ? (m >= 1 && m <= 3)
                                         : (m >= 4 && m <= 8);
                if (valid)
                    msgF[m*128 + k] = acc[i] + SY[m]*b3[col]*wemb[k]*0.0625f;
            }
        }
    }
    __syncthreads();

    if (t < 128) {
        float acc = 0.f;
        #pragma unroll
        for (int m = 4; m < 9; m++) { float v = msgF[m*128 + t]; acc += v*v; }
        qF[t] = acc;
    }
    __syncthreads();

    // A2 [16][392]: row0 = [msg0 | q | 0]; rows1-3 = [0 | 0 | msg_m]; rest 0
    for (int idx = t; idx < 6272; idx += 256) A2[idx] = 0;
    __syncthreads();
    {
        int idx = t;   // 256 threads cover row0's 256 entries
        A2[idx] = (idx < 128) ? f2bf(msgF[idx]) : f2bf(qF[idx - 128]);
        if (t < 128) {
            #pragma unroll
            for (int m = 1; m <= 3; m++)
                A2[m*392 + 256 + t] = f2bf(msgF[m*128 + t]);
        }
    }
    __syncthreads();

    // s1v1 GEMM: D2[16][128] = A2[16][384] @ lT (n-tiles: wave wv -> 2wv, 2wv+1)
    #pragma unroll
    for (int tt = 0; tt < 2; tt++) {
        int col = (wv*2 + tt)*16 + nn;
        floatx4 acc = (floatx4){0.f, 0.f, 0.f, 0.f};
        #pragma unroll
        for (int ks = 0; ks < 384; ks += 32) {
            bf16x8 a = ld_frag(&A2[nn*392 + ks + qd*8]);
            bf16x8 bfr = ld_frag(&lT[(size_t)col*384 + ks + qd*8]);
            acc = __builtin_amdgcn_mfma_f32_16x16x32_bf16(a, bfr, acc, 0, 0, 0);
        }
        if (qd == 0) {
            float s1 = acc[0];
            featsb[(size_t)node*704 + col] = f2bf(s1);
            h1g[(size_t)node*128 + col] = silu_f(s1);
            #pragma unroll
            for (int i = 1; i < 4; i++) {
                float v = acc[i];
                v1g[(size_t)node*384 + (i-1)*128 + col] = v;
                featsb[(size_t)node*704 + 128 + (i-1)*128 + col] = f2bf(v);
            }
        }
    }
    if (t == 0) featsb[(size_t)node*704 + 640] = f2bf(timeg[b]);
    if (t < 63) featsb[(size_t)node*704 + 641 + t] = 0;
}

// ---------------------------------------------------------------------------
// Kernel 3 (pass 2): L0/L1/L2 MFMA; h1/inv pre-staged to LDS bf16; we2 via
// MFMA from hc; epilogue all-LDS; s2 = msgab@mix2/16.
// ---------------------------------------------------------------------------
__global__ __launch_bounds__(256) void pass2_kernel(
    const float* __restrict__ rad, const float* __restrict__ Y1g,
    const float* __restrict__ maskg,
    const short* __restrict__ w0T, const float* __restrict__ b0,
    const short* __restrict__ w1T, const float* __restrict__ b1,
    const short* __restrict__ w2T, const float* __restrict__ b2,
    const short* __restrict__ w3T, const float* __restrict__ b3,
    const float* __restrict__ mix2,
    const float* __restrict__ h1g, const float* __restrict__ v1g,
    short* __restrict__ featsb)
{
    // Pool (bytes): radB [0,5120) ; hc [0,9216) after L2 ;
    // actA [9216,18432) ; actB [18432,27648) ;
    // h1B [9216,26624) after L2 ; invB [27648,45056) ;
    // Y1s [45056,46080) ; mask_s [46080,46336) ; msgab [46336,46848)
    __shared__ __align__(16) char pool[46848];
    short* radB  = (short*)pool;
    short* hc    = (short*)pool;
    short* actA  = (short*)(pool + 9216);
    short* actB  = (short*)(pool + 18432);
    short* h1B   = (short*)(pool + 9216);    // [64][136]
    short* invB  = (short*)(pool + 27648);   // [64][136]
    float* Y1s   = (float*)(pool + 45056);   // [64*4]
    float* mask_s= (float*)(pool + 46080);   // [64]
    float* msgab = (float*)(pool + 46336);   // [128]

    int t = threadIdx.x;
    int wv = t >> 6, lane = t & 63, qd = lane >> 4, nn = lane & 15;
    int node = blockIdx.x;
    int b = node >> 6;
    size_t pbase = (size_t)node * 64;

    for (int idx = t; idx < 2560; idx += 256) {
        int j = idx / 40, c = idx - j*40;
        radB[idx] = (c < 8) ? f2bf(rad[pbase*8 + j*8 + c]) : (short)0;
    }
    if (t < 64) {
        mask_s[t] = maskg[pbase + t];
        #pragma unroll
        for (int m = 0; m < 3; m++) Y1s[t*4 + m] = Y1g[(pbase+t)*3 + m];
    }
    if (t < 128) msgab[t] = 0.f;
    __syncthreads();

    mfma_layer0(radB, w0T, b0, actA, wv, qd, nn);
    __syncthreads();
    mfma_layer_t<false>(actA, w1T, b1, actB, wv, qd, nn);
    __syncthreads();
    mfma_layer_t<false>(actB, w2T, b2, hc, wv, qd, nn);     // hc[j][h]
    __syncthreads();

    // stage h1B and invB (bf16), float4 global loads
    for (int idx = t; idx < 2048; idx += 256) {
        int j = idx >> 5, kq = (idx & 31)*4;
        size_t gj = (size_t)b*64 + j;
        float4 hv = ld4(&h1g[gj*128 + kq]);
        h1B[j*136 + kq + 0] = f2bf(hv.x);
        h1B[j*136 + kq + 1] = f2bf(hv.y);
        h1B[j*136 + kq + 2] = f2bf(hv.z);
        h1B[j*136 + kq + 3] = f2bf(hv.w);
        const float* vb = &v1g[gj*384 + kq];
        float4 vx = ld4(vb), vy = ld4(vb + 128), vz = ld4(vb + 256);
        float yx = Y1s[j*4+0], yy = Y1s[j*4+1], yz = Y1s[j*4+2];
        invB[j*136 + kq + 0] = f2bf(yx*vx.x + yy*vy.x + yz*vz.x);
        invB[j*136 + kq + 1] = f2bf(yx*vx.y + yy*vy.y + yz*vz.y);
        invB[j*136 + kq + 2] = f2bf(yx*vx.z + yy*vy.z + yz*vz.z);
        invB[j*136 + kq + 3] = f2bf(yx*vx.w + yy*vy.w + yz*vz.w);
    }
    __syncthreads();

    // we2: [64j][256col] = hc @ w3T; epilogue folds mask, h1/inv, reduce
    {
        bf16x8 aA = ld_frag(&hc[(wv*16 + nn)*72 + 0  + qd*8]);
        bf16x8 aB = ld_frag(&hc[(wv*16 + nn)*72 + 32 + qd*8]);
        #pragma unroll
        for (int g = 0; g < 4; g++) {
            #pragma unroll
            for (int tt = 0; tt < 4; tt++) {
                int col0 = g*64 + tt*16;
                floatx4 acc = (floatx4){0.f, 0.f, 0.f, 0.f};
                bf16x8 b0f = ld_frag(&w3T[(col0 + nn)*64 + 0  + qd*8]);
                bf16x8 b1f = ld_frag(&w3T[(col0 + nn)*64 + 32 + qd*8]);
                acc = __builtin_amdgcn_mfma_f32_16x16x32_bf16(aA, b0f, acc, 0, 0, 0);
                acc = __builtin_amdgcn_mfma_f32_16x16x32_bf16(aB, b1f, acc, 0, 0, 0);
                int col = col0 + nn;
                int k = col & 127;
                float bias = b3[col];
                const short* src = (col < 128) ? h1B : invB;
                float p = 0.f;
                #pragma unroll
                for (int i = 0; i < 4; i++) {
                    int j = wv*16 + qd*4 + i;
                    float we = (acc[i] + bias) * mask_s[j];
                    p += we * bf2f(src[j*136 + k]);
                }
                p += __shfl_xor(p, 16);
                p += __shfl_xor(p, 32);
                if (qd == 0) atomicAdd(&msgab[k], p);
            }
        }
    }
    __syncthreads();

    if (t < 128) {
        float acc = 0.f;
        for (int k = 0; k < 128; k++) acc += msgab[k] * mix2[k*128 + t];
        featsb[(size_t)node*704 + 512 + t] = f2bf(acc * 0.0625f);
    }
}

// ---------------------------------------------------------------------------
// Kernel 4: bf16 MFMA GEMM, C = relu(A[M][lda] @ BT^T + bias) -> bf16
// ---------------------------------------------------------------------------
__global__ __launch_bounds__(256) void gemm_mfma_kernel(
    const short* __restrict__ A, int lda,
    const short* __restrict__ BT, int ldb, int K,
    const float* __restrict__ bias, short* __restrict__ Cout, int ldo)
{
    __shared__ short As[64*72];
    __shared__ short Bs[64*72];
    int t = threadIdx.x;
    int wv = t >> 6, lane = t & 63, qd = lane >> 4, nn = lane & 15;
    int m0 = blockIdx.x * 64, n0 = blockIdx.y * 64;
    floatx4 acc[4];
    #pragma unroll
    for (int tt = 0; tt < 4; tt++) acc[tt] = (floatx4){0.f, 0.f, 0.f, 0.f};

    for (int kc = 0; kc < K; kc += 64) {
        for (int s = t; s < 512; s += 256) {
            int j = s >> 3, kk = (s & 7) * 8;
            *(uint4*)&As[j*72 + kk] = *(const uint4*)&A[(size_t)(m0 + j)*lda + kc + kk];
            *(uint4*)&Bs[j*72 + kk] = *(const uint4*)&BT[(size_t)(n0 + j)*ldb + kc + kk];
        }
        __syncthreads();
        #pragma unroll
        for (int ks = 0; ks < 64; ks += 32) {
            bf16x8 a = ld_frag(&As[(wv*16 + nn)*72 + ks + qd*8]);
            #pragma unroll
            for (int tt = 0; tt < 4; tt++) {
                bf16x8 bb = ld_frag(&Bs[(tt*16 + nn)*72 + ks + qd*8]);
                acc[tt] = __builtin_amdgcn_mfma_f32_16x16x32_bf16(a, bb, acc[tt], 0, 0, 0);
            }
        }
        __syncthreads();
    }
    #pragma unroll
    for (int tt = 0; tt < 4; tt++) {
        int n = n0 + tt*16 + nn;
        float bv = bias[n];
        #pragma unroll
        for (int i = 0; i < 4; i++) {
            int m = m0 + wv*16 + qd*4 + i;
            Cout[(size_t)m*ldo + n] = f2bf(fmaxf(acc[tt][i] + bv, 0.f));
        }
    }
}

// ---------------------------------------------------------------------------
// Kernel 5: out[node,3] = H(bf16)[node,512] @ w2[512,3] + b2
// ---------------------------------------------------------------------------
__global__ __launch_bounds__(64) void final3_kernel(
    const short* __restrict__ H, const float* __restrict__ w2,
    const float* __restrict__ b2, float* __restrict__ out)
{
    int node = blockIdx.x, lane = threadIdx.x;
    float a0 = 0.f, a1 = 0.f, a2 = 0.f;
    #pragma unroll
    for (int r = 0; r < 8; r++) {
        int k = r*64 + lane;
        float h = bf2f(H[(size_t)node*512 + k]);
        a0 += h * w2[k*3 + 0];
        a1 += h * w2[k*3 + 1];
        a2 += h * w2[k*3 + 2];
    }
    #pragma unroll
    for (int off = 32; off > 0; off >>= 1) {
        a0 += __shfl_down(a0, off);
        a1 += __shfl_down(a1, off);
        a2 += __shfl_down(a2, off);
    }
    if (lane == 0) {
        out[(size_t)node*3 + 0] = a0 + b2[0];
        out[(size_t)node*3 + 1] = a1 + b2[1];
        out[(size_t)node*3 + 2] = a2 + b2[2];
    }
}

extern "C" void kernel_launch(void* const* d_in, const int* in_sizes, int n_in,
                              void* d_out, int out_size, void* d_ws, size_t ws_size,
                              hipStream_t stream) {
    const float* pos   = (const float*)d_in[0];
    const float* timeg = (const float*)d_in[1];
    const float* cell  = (const float*)d_in[2];
    const float* wemb  = (const float*)d_in[3];
    const float* r1w0  = (const float*)d_in[4];
    const float* r1b0  = (const float*)d_in[5];
    const float* r1w1  = (const float*)d_in[6];
    const float* r1b1  = (const float*)d_in[7];
    const float* r1w2  = (const float*)d_in[8];
    const float* r1b2  = (const float*)d_in[9];
    const float* r1w3  = (const float*)d_in[10];
    const float* r1b3  = (const float*)d_in[11];
    const float* l0    = (const float*)d_in[12];
    const float* l1    = (const float*)d_in[13];
    const float* l2    = (const float*)d_in[14];
    const float* r2w0  = (const float*)d_in[15];
    const float* r2b0  = (const float*)d_in[16];
    const float* r2w1  = (const float*)d_in[17];
    const float* r2b1  = (const float*)d_in[18];
    const float* r2w2  = (const float*)d_in[19];
    const float* r2b2  = (const float*)d_in[20];
    const float* r2w3  = (const float*)d_in[21];
    const float* r2b3  = (const float*)d_in[22];
    const float* mix2  = (const float*)d_in[23];
    const float* mw0   = (const float*)d_in[24];
    const float* mb0   = (const float*)d_in[25];
    const float* mw1   = (const float*)d_in[26];
    const float* mb1   = (const float*)d_in[27];
    const float* mw2   = (const float*)d_in[28];
    const float* mb2   = (const float*)d_in[29];

    float* ws    = (float*)d_ws;
    float* rad   = ws;                                   // 1,048,576 f
    float* Y1    = rad   + (size_t)NPAIR*8;              //   393,216 f
    float* Y2    = Y1    + (size_t)NPAIR*3;              //   655,360 f
    float* maskf = Y2    + (size_t)NPAIR*5;              //   131,072 f
    float* h1    = maskf + (size_t)NPAIR;                //   262,144 f
    float* v1    = h1    + (size_t)B_*N_*K_;             //   786,432 f
    short* featsb = (short*)(v1 + (size_t)B_*N_*3*K_);   // 2048*704 sh
    short* prep  = featsb + (size_t)2048*704;            //   733,184 sh
    short* w1T_1 = prep;
    short* w2T_1 = prep + 4096;
    short* w1T_2 = prep + 8192;
    short* w2T_2 = prep + 12288;
    short* w3T_2 = prep + 16384;
    short* wT0   = prep + 32768;     // [512][704]
    short* wT1   = prep + 393216;    // [512][512]
    short* w0T_1 = prep + 655360;    // [64][32]
    short* w0T_2 = prep + 657408;    // [64][32]
    short* w3T_1 = prep + 659456;    // [384][64]
    short* lT    = prep + 684032;    // [128][384]
    short* h0bb = (short*)rad;       // 2048x512 bf16, aliases dead rad
    short* h1bb = (short*)Y2;        // 2048x512 bf16, aliases dead Y2

    prep_kernel<<<(733184 + 255)/256, 256, 0, stream>>>(
        r1w0, r1w1, r1w2, r1w3, r2w0, r2w1, r2w2, r2w3, mw0, mw1,
        wemb, l0, l1, l2, prep);
    geom_kernel<<<NPAIR/256, 256, 0, stream>>>(pos, cell, rad, Y1, Y2, maskf);
    pass1_kernel<<<B_*N_, 256, 0, stream>>>(rad, Y1, Y2, maskf, wemb,
        w0T_1, r1b0, w1T_1, r1b1, w2T_1, r1b2, w3T_1, r1b3, lT, timeg,
        h1, v1, featsb);
    pass2_kernel<<<B_*N_, 256, 0, stream>>>(rad, Y1, maskf,
        w0T_2, r2b0, w1T_2, r2b1, w2T_2, r2b2, w3T_2, r2b3, mix2, h1, v1, featsb);
    dim3 g0(32, 8);
    gemm_mfma_kernel<<<g0, 256, 0, stream>>>(featsb, 704, wT0, 704, 704, mb0, h0bb, 512);
    gemm_mfma_kernel<<<g0, 256, 0, stream>>>(h0bb, 512, wT1, 512, 512, mb1, h1bb, 512);
    final3_kernel<<<B_*N_, 64, 0, stream>>>(h1bb, mw2, mb2, (float*)d_out);
}